// Round 1
// baseline (3976.897 us; speedup 1.0000x reference)
//
#include <hip/hip_runtime.h>
#include <cstddef>

// Problem constants
#define BB_ 32
#define SS_ 256
#define HH_ 256
#define NHH 8
#define DHH 32

#define DEV __device__ __forceinline__

DEV float fexp2(float x) { return __builtin_amdgcn_exp2f(x); }
DEV float frcp(float x)  { return __builtin_amdgcn_rcpf(x); }
DEV float fsigm(float x) { return frcp(1.0f + fexp2(-1.44269504f * x)); }
DEV float ftanh_(float x){ return 1.0f - 2.0f * frcp(1.0f + fexp2(2.88539008f * x)); }

// ---------------------------------------------------------------------------
// Generic fp32 GEMM: C[M,N] = A[M,K] @ W[N,K]^T + bias1 (+bias2), optional relu
// BM=128, BK=16, 256 threads, micro-tile 8 x (BN/16). LDS padded +4 (2-way max).
// ---------------------------------------------------------------------------
template <int BN, bool RELU>
__global__ __launch_bounds__(256) void gemm_kernel(
    const float* __restrict__ A, const float* __restrict__ W,
    const float* __restrict__ bias1, const float* __restrict__ bias2,
    float* __restrict__ C, int M, int N, int K)
{
    constexpr int BM = 128, BK = 16;
    constexpr int NC = BN / 64;           // col-halves (1 or 2)
    __shared__ float As[BK][BM + 4];
    __shared__ float Bs[BK][BN + 4];

    const int tid = threadIdx.x;
    const int tx = tid & 15, ty = tid >> 4;
    const int m0 = blockIdx.x * BM, n0 = blockIdx.y * BN;

    float acc[2][NC][4][4];
#pragma unroll
    for (int rh = 0; rh < 2; ++rh)
#pragma unroll
        for (int ch = 0; ch < NC; ++ch)
#pragma unroll
            for (int i = 0; i < 4; ++i)
#pragma unroll
                for (int j = 0; j < 4; ++j) acc[rh][ch][i][j] = 0.f;

    for (int k0 = 0; k0 < K; k0 += BK) {
        // stage A tile (BM x BK), transposed into As[kk][m]
#pragma unroll
        for (int l = 0; l < 2; ++l) {
            int idx = tid + l * 256;            // 0..511 float4s
            int row = idx >> 2, kc4 = idx & 3;
            float4 v = *(const float4*)&A[(size_t)(m0 + row) * K + k0 + kc4 * 4];
            As[kc4 * 4 + 0][row] = v.x; As[kc4 * 4 + 1][row] = v.y;
            As[kc4 * 4 + 2][row] = v.z; As[kc4 * 4 + 3][row] = v.w;
        }
        // stage B tile (BN x BK) from W[N,K]
#pragma unroll
        for (int l = 0; l < BN / 64; ++l) {
            int idx = tid + l * 256;
            int row = idx >> 2, kc4 = idx & 3;
            float4 v = *(const float4*)&W[(size_t)(n0 + row) * K + k0 + kc4 * 4];
            Bs[kc4 * 4 + 0][row] = v.x; Bs[kc4 * 4 + 1][row] = v.y;
            Bs[kc4 * 4 + 2][row] = v.z; Bs[kc4 * 4 + 3][row] = v.w;
        }
        __syncthreads();
#pragma unroll
        for (int kk = 0; kk < BK; ++kk) {
            const float4 a0 = *(const float4*)&As[kk][ty * 4];
            const float4 a1 = *(const float4*)&As[kk][64 + ty * 4];
            float ar[2][4] = {{a0.x, a0.y, a0.z, a0.w}, {a1.x, a1.y, a1.z, a1.w}};
            float br[NC][4];
            const float4 b0 = *(const float4*)&Bs[kk][tx * 4];
            br[0][0] = b0.x; br[0][1] = b0.y; br[0][2] = b0.z; br[0][3] = b0.w;
            if (NC == 2) {
                const float4 b1 = *(const float4*)&Bs[kk][64 + tx * 4];
                br[1][0] = b1.x; br[1][1] = b1.y; br[1][2] = b1.z; br[1][3] = b1.w;
            }
#pragma unroll
            for (int rh = 0; rh < 2; ++rh)
#pragma unroll
                for (int ch = 0; ch < NC; ++ch)
#pragma unroll
                    for (int i = 0; i < 4; ++i)
#pragma unroll
                        for (int j = 0; j < 4; ++j)
                            acc[rh][ch][i][j] += ar[rh][i] * br[ch][j];
        }
        __syncthreads();
    }

#pragma unroll
    for (int ch = 0; ch < NC; ++ch) {
        int col = n0 + ch * 64 + tx * 4;
        float4 bv = *(const float4*)&bias1[col];
        if (bias2) {
            float4 b2 = *(const float4*)&bias2[col];
            bv.x += b2.x; bv.y += b2.y; bv.z += b2.z; bv.w += b2.w;
        }
#pragma unroll
        for (int rh = 0; rh < 2; ++rh)
#pragma unroll
            for (int i = 0; i < 4; ++i) {
                int row = m0 + rh * 64 + ty * 4 + i;
                float4 r;
                r.x = acc[rh][ch][i][0] + bv.x;
                r.y = acc[rh][ch][i][1] + bv.y;
                r.z = acc[rh][ch][i][2] + bv.z;
                r.w = acc[rh][ch][i][3] + bv.w;
                if (RELU) {
                    r.x = fmaxf(r.x, 0.f); r.y = fmaxf(r.y, 0.f);
                    r.z = fmaxf(r.z, 0.f); r.w = fmaxf(r.w, 0.f);
                }
                *(float4*)&C[(size_t)row * N + col] = r;
            }
    }
}

// ---------------------------------------------------------------------------
// Bin encoder: bb = relu(bin_info @ W1^T + b1) @ W2^T + b2   [B,64]
// ---------------------------------------------------------------------------
__global__ __launch_bounds__(64) void bin_enc_kernel(
    const float* __restrict__ bin_info, const float* __restrict__ W1,
    const float* __restrict__ b1, const float* __restrict__ W2,
    const float* __restrict__ b2, float* __restrict__ BBo)
{
    int b = blockIdx.x, d = threadIdx.x;
    __shared__ float h1[64];
    float x0 = bin_info[b * 2], x1 = bin_info[b * 2 + 1];
    h1[d] = fmaxf(W1[d * 2] * x0 + W1[d * 2 + 1] * x1 + b1[d], 0.f);
    __syncthreads();
    float acc = b2[d];
#pragma unroll 4
    for (int e = 0; e < 64; ++e) acc += W2[d * 64 + e] * h1[e];
    BBo[b * 64 + d] = acc;
}

// ---------------------------------------------------------------------------
// Part encoder + concat: X[b,s,:] = [p(128) | bb(64) | pos(64)]
// grid 256 = (b, s-chunk of 32), 128 threads
// ---------------------------------------------------------------------------
__global__ __launch_bounds__(128) void part_enc_kernel(
    const float* __restrict__ parts, const float* __restrict__ W1,
    const float* __restrict__ b1, const float* __restrict__ W2,
    const float* __restrict__ b2, const float* __restrict__ BBi,
    const float* __restrict__ pos_emb, float* __restrict__ X)
{
    __shared__ float W2s[128][129];
    __shared__ float h1[128];
    __shared__ float pin[16];
    int tid = threadIdx.x;
    int b = blockIdx.x >> 3, s0 = (blockIdx.x & 7) * 32;
    for (int l = 0; l < 128; ++l) W2s[l][tid] = W2[l * 128 + tid];
    float w1r[16];
#pragma unroll
    for (int k = 0; k < 16; ++k) w1r[k] = W1[tid * 16 + k];
    float bias1v = b1[tid], bias2v = b2[tid];
    for (int si = 0; si < 32; ++si) {
        int s = s0 + si;
        size_t row = (size_t)b * 256 + s;
        if (tid < 16) pin[tid] = parts[row * 16 + tid];
        __syncthreads();
        float h = bias1v;
#pragma unroll
        for (int k = 0; k < 16; ++k) h += w1r[k] * pin[k];
        h1[tid] = fmaxf(h, 0.f);
        __syncthreads();
        float acc = bias2v;
#pragma unroll 4
        for (int e = 0; e < 128; ++e) acc += W2s[tid][e] * h1[e];
        X[row * 256 + tid] = acc;
        if (tid < 64) {
            X[row * 256 + 128 + tid] = BBi[b * 64 + tid];
            X[row * 256 + 192 + tid] = pos_emb[s * 64 + tid];
        }
        __syncthreads();
    }
}

// ---------------------------------------------------------------------------
// Attention: one block per (b, head). qkv packed [B,S,768]. O [B,S,256].
// Two-pass softmax (recompute scores), q/o in registers, k/v in LDS.
// ---------------------------------------------------------------------------
__global__ __launch_bounds__(256) void attn_kernel(
    const float* __restrict__ QKV, float* __restrict__ O)
{
    int bh = blockIdx.x;
    int b = bh >> 3, h = bh & 7;
    int s = threadIdx.x;
    __shared__ float k_s[256][36];
    __shared__ float v_s[256][36];
    const float scale = 0.17677669529663687f;
    const float c_log2e = 1.44269504f;

    const float* base = QKV + ((size_t)(b * 256 + s)) * 768 + h * 32;
    float q[32];
#pragma unroll
    for (int d4 = 0; d4 < 8; ++d4) {
        float4 qv = *(const float4*)(base + d4 * 4);
        q[d4 * 4 + 0] = qv.x; q[d4 * 4 + 1] = qv.y;
        q[d4 * 4 + 2] = qv.z; q[d4 * 4 + 3] = qv.w;
        float4 kv = *(const float4*)(base + 256 + d4 * 4);
        *(float4*)&k_s[s][d4 * 4] = kv;
        float4 vv = *(const float4*)(base + 512 + d4 * 4);
        *(float4*)&v_s[s][d4 * 4] = vv;
    }
    __syncthreads();

    float mmax = -1e30f;
    for (int j = 0; j < 256; ++j) {
        float sc = 0.f;
#pragma unroll
        for (int d4 = 0; d4 < 8; ++d4) {
            float4 kv = *(const float4*)&k_s[j][d4 * 4];
            sc += q[d4 * 4 + 0] * kv.x + q[d4 * 4 + 1] * kv.y
                + q[d4 * 4 + 2] * kv.z + q[d4 * 4 + 3] * kv.w;
        }
        mmax = fmaxf(mmax, sc);
    }
    float sum = 0.f;
    float o[32];
#pragma unroll
    for (int d = 0; d < 32; ++d) o[d] = 0.f;
    for (int j = 0; j < 256; ++j) {
        float sc = 0.f;
#pragma unroll
        for (int d4 = 0; d4 < 8; ++d4) {
            float4 kv = *(const float4*)&k_s[j][d4 * 4];
            sc += q[d4 * 4 + 0] * kv.x + q[d4 * 4 + 1] * kv.y
                + q[d4 * 4 + 2] * kv.z + q[d4 * 4 + 3] * kv.w;
        }
        float e = fexp2((sc - mmax) * (scale * c_log2e));
        sum += e;
#pragma unroll
        for (int d4 = 0; d4 < 8; ++d4) {
            float4 vv = *(const float4*)&v_s[j][d4 * 4];
            o[d4 * 4 + 0] += e * vv.x; o[d4 * 4 + 1] += e * vv.y;
            o[d4 * 4 + 2] += e * vv.z; o[d4 * 4 + 3] += e * vv.w;
        }
    }
    float inv = 1.0f / sum;
    float* op = O + ((size_t)(b * 256 + s)) * 256 + h * 32;
#pragma unroll
    for (int d4 = 0; d4 < 8; ++d4) {
        float4 r;
        r.x = o[d4 * 4 + 0] * inv; r.y = o[d4 * 4 + 1] * inv;
        r.z = o[d4 * 4 + 2] * inv; r.w = o[d4 * 4 + 3] * inv;
        *(float4*)(op + d4 * 4) = r;
    }
}

// ---------------------------------------------------------------------------
// Residual add + LayerNorm (in place on X). One block per row, 256 threads.
// ---------------------------------------------------------------------------
__global__ __launch_bounds__(256) void add_ln_kernel(
    float* __restrict__ X, const float* __restrict__ R,
    const float* __restrict__ g, const float* __restrict__ beta)
{
    size_t row = blockIdx.x;
    int d = threadIdx.x;
    float y = X[row * 256 + d] + R[row * 256 + d];
    float s = y, s2 = y * y;
#pragma unroll
    for (int o = 32; o; o >>= 1) {
        s += __shfl_down(s, o);
        s2 += __shfl_down(s2, o);
    }
    __shared__ float red[8];
    int wid = d >> 6, lane = d & 63;
    if (lane == 0) { red[wid] = s; red[4 + wid] = s2; }
    __syncthreads();
    if (d == 0) {
        float a = 0.f, b2 = 0.f;
        for (int w = 0; w < 4; ++w) { a += red[w]; b2 += red[4 + w]; }
        red[0] = a * (1.f / 256.f);
        red[1] = b2 * (1.f / 256.f);
    }
    __syncthreads();
    float m = red[0];
    float var = red[1] - m * m;
    float inv = rsqrtf(var + 1e-5f);
    X[row * 256 + d] = (y - m) * inv * g[d] + beta[d];
}

// ---------------------------------------------------------------------------
// Gather teacher-forced LSTM inputs: Xg[b,0]=0; Xg[b,t]=enc[b,target[b,t-1]]
// ---------------------------------------------------------------------------
__global__ __launch_bounds__(256) void gather_kernel(
    const float* __restrict__ X, const int* __restrict__ target,
    float* __restrict__ Xg)
{
    int row = blockIdx.x;            // b*256 + t
    int b = row >> 8, t = row & 255;
    int d = threadIdx.x;
    float val = 0.f;
    if (t > 0) {
        int src = target[b * 256 + t - 1];
        val = X[((size_t)b * 256 + src) * 256 + d];
    }
    Xg[(size_t)row * 256 + d] = val;
}

// Whh [1024,256] -> WhhT [256,1024]  (WhhT[k*1024 + j] = Whh[j*256 + k])
__global__ __launch_bounds__(256) void transpose_kernel(
    const float* __restrict__ Whh, float* __restrict__ WT)
{
    int o = blockIdx.x * 256 + threadIdx.x;   // 0..262143
    int k = o >> 10, j = o & 1023;
    WT[o] = Whh[j * 256 + k];
}

// ---------------------------------------------------------------------------
// LSTM recurrence: one block per batch element, 256 threads, 256 steps.
// g_in already holds xin@Wih^T + bih + bhh. Thread j owns gate rows 4j..4j+3
// for the matvec, then cell dim j for the elementwise update.
// ---------------------------------------------------------------------------
__global__ __launch_bounds__(256) void lstm_kernel(
    const float* __restrict__ g_in, const float* __restrict__ WT,
    float* __restrict__ HALL)
{
    int b = blockIdx.x;
    int tid = threadIdx.x;
    __shared__ float h_s[256];
    __shared__ float g_s[1024];
    float c = 0.f;
    h_s[tid] = 0.f;
    __syncthreads();
    const float4* WT4 = (const float4*)WT;
    for (int t = 0; t < 256; ++t) {
        const float* gin = g_in + (((size_t)b << 8) + t) * 1024;
        float4 g4 = *(const float4*)(gin + tid * 4);
#pragma unroll 4
        for (int k = 0; k < 256; ++k) {
            float4 w = WT4[k * 256 + tid];
            float hk = h_s[k];
            g4.x += w.x * hk; g4.y += w.y * hk;
            g4.z += w.z * hk; g4.w += w.w * hk;
        }
        *(float4*)&g_s[tid * 4] = g4;
        __syncthreads();
        float ig = g_s[tid], fg = g_s[tid + 256];
        float gg = g_s[tid + 512], og = g_s[tid + 768];
        c = fsigm(fg) * c + fsigm(ig) * ftanh_(gg);
        float h = fsigm(og) * ftanh_(c);
        h_s[tid] = h;
        HALL[(((size_t)b << 8) + t) * 256 + tid] = h;
        __syncthreads();
    }
}

// ---------------------------------------------------------------------------
// Pointer logits: out[b,t,i] = sum_d v[d]*tanh(hp[b,t,d] + ep[b,i,d])
// block = (it, tt, b) 16x16 tile, 256 threads (one (t,i) pair each)
// ---------------------------------------------------------------------------
__global__ __launch_bounds__(256) void pointer_kernel(
    const float* __restrict__ HP, const float* __restrict__ EP,
    const float* __restrict__ v, float* __restrict__ out)
{
    int b = blockIdx.z, tt = blockIdx.y, it = blockIdx.x;
    __shared__ float hp_s[16][260];
    __shared__ float ep_s[16][260];
    __shared__ float v_s[256];
    int tid = threadIdx.x;
    const float* hpb = HP + ((size_t)b * 256 + tt * 16) * 256;
    const float* epb = EP + ((size_t)b * 256 + it * 16) * 256;
#pragma unroll
    for (int l = 0; l < 4; ++l) {
        int idx = tid + l * 256;          // 0..1023 float4s
        int r = idx >> 6, c4 = idx & 63;
        float4 hv = *(const float4*)(hpb + r * 256 + c4 * 4);
        *(float4*)&hp_s[r][c4 * 4] = hv;
        float4 ev = *(const float4*)(epb + r * 256 + c4 * 4);
        *(float4*)&ep_s[r][c4 * 4] = ev;
    }
    v_s[tid] = v[tid];
    __syncthreads();
    int tl = tid >> 4, il = tid & 15;
    float acc = 0.f;
#pragma unroll 4
    for (int d = 0; d < 256; ++d)
        acc += v_s[d] * ftanh_(hp_s[tl][d] + ep_s[il][d]);
    out[((size_t)b * 256 + tt * 16 + tl) * 256 + it * 16 + il] = acc;
}

// ---------------------------------------------------------------------------
extern "C" void kernel_launch(void* const* d_in, const int* in_sizes, int n_in,
                              void* d_out, int out_size, void* d_ws, size_t ws_size,
                              hipStream_t stream)
{
    const float* parts    = (const float*)d_in[0];
    const float* bin_info = (const float*)d_in[1];
    const int*   target   = (const int*)d_in[2];
    const float* pe_W1 = (const float*)d_in[3];
    const float* pe_b1 = (const float*)d_in[4];
    const float* pe_W2 = (const float*)d_in[5];
    const float* pe_b2 = (const float*)d_in[6];
    const float* be_W1 = (const float*)d_in[7];
    const float* be_b1 = (const float*)d_in[8];
    const float* be_W2 = (const float*)d_in[9];
    const float* be_b2 = (const float*)d_in[10];
    const float* pos_emb = (const float*)d_in[11];
    const float* tr_Wqkv = (const float*)d_in[12];
    const float* tr_bqkv = (const float*)d_in[13];
    const float* tr_Wo   = (const float*)d_in[14];
    const float* tr_bo   = (const float*)d_in[15];
    const float* tr_ln1_g = (const float*)d_in[16];
    const float* tr_ln1_b = (const float*)d_in[17];
    const float* tr_ff_W1 = (const float*)d_in[18];
    const float* tr_ff_b1 = (const float*)d_in[19];
    const float* tr_ff_W2 = (const float*)d_in[20];
    const float* tr_ff_b2 = (const float*)d_in[21];
    const float* tr_ln2_g = (const float*)d_in[22];
    const float* tr_ln2_b = (const float*)d_in[23];
    const float* lstm_Wih = (const float*)d_in[24];
    const float* lstm_Whh = (const float*)d_in[25];
    const float* lstm_bih = (const float*)d_in[26];
    const float* lstm_bhh = (const float*)d_in[27];
    const float* ptr_W = (const float*)d_in[28];
    const float* ptr_b = (const float*)d_in[29];
    const float* ptr_v = (const float*)d_in[30];

    float* ws = (float*)d_ws;
    float* X     = ws;                   // 8192*256  = 2,097,152
    float* S1    = X + 2097152;          // 8192*1024 = 8,388,608
    float* S2    = S1 + 8388608;         // 8192*256  = 2,097,152
    float* EPROJ = S2 + 2097152;         // 2,097,152
    float* BBuf  = EPROJ + 2097152;      // 2048
    float* WHHT  = BBuf + 2048;          // 262,144
    float* HALL  = WHHT + 262144;        // 2,097,152
    // total ~68.2 MB of d_ws

    // ---- encoders ----
    bin_enc_kernel<<<32, 64, 0, stream>>>(bin_info, be_W1, be_b1, be_W2, be_b2, BBuf);
    part_enc_kernel<<<256, 128, 0, stream>>>(parts, pe_W1, pe_b1, pe_W2, pe_b2,
                                             BBuf, pos_emb, X);

    // ---- transformer layers ----
    for (int l = 0; l < 3; ++l) {
        gemm_kernel<128, false><<<dim3(64, 6), 256, 0, stream>>>(
            X, tr_Wqkv + (size_t)l * 768 * 256, tr_bqkv + l * 768, nullptr,
            S1, 8192, 768, 256);
        attn_kernel<<<256, 256, 0, stream>>>(S1, S2);
        gemm_kernel<64, false><<<dim3(64, 4), 256, 0, stream>>>(
            S2, tr_Wo + (size_t)l * 256 * 256, tr_bo + l * 256, nullptr,
            S1, 8192, 256, 256);
        add_ln_kernel<<<8192, 256, 0, stream>>>(X, S1, tr_ln1_g + l * 256,
                                                tr_ln1_b + l * 256);
        gemm_kernel<128, true><<<dim3(64, 4), 256, 0, stream>>>(
            X, tr_ff_W1 + (size_t)l * 512 * 256, tr_ff_b1 + l * 512, nullptr,
            S1, 8192, 512, 256);
        gemm_kernel<64, false><<<dim3(64, 4), 256, 0, stream>>>(
            S1, tr_ff_W2 + (size_t)l * 256 * 512, tr_ff_b2 + l * 256, nullptr,
            S2, 8192, 256, 512);
        add_ln_kernel<<<8192, 256, 0, stream>>>(X, S2, tr_ln2_g + l * 256,
                                                tr_ln2_b + l * 256);
    }

    // ---- pointer decode ----
    gemm_kernel<64, false><<<dim3(64, 4), 256, 0, stream>>>(
        X, ptr_W, ptr_b, nullptr, EPROJ, 8192, 256, 256);
    gather_kernel<<<8192, 256, 0, stream>>>(X, target, S2);
    gemm_kernel<128, false><<<dim3(64, 8), 256, 0, stream>>>(
        S2, lstm_Wih, lstm_bih, lstm_bhh, S1, 8192, 1024, 256);
    transpose_kernel<<<1024, 256, 0, stream>>>(lstm_Whh, WHHT);
    lstm_kernel<<<32, 256, 0, stream>>>(S1, WHHT, HALL);
    gemm_kernel<64, false><<<dim3(64, 4), 256, 0, stream>>>(
        HALL, ptr_W, ptr_b, nullptr, S2, 8192, 256, 256);
    pointer_kernel<<<dim3(16, 16, 32), 256, 0, stream>>>(S2, EPROJ, ptr_v,
                                                         (float*)d_out);
}

// Round 2
// 3284.602 us; speedup vs baseline: 1.2108x; 1.2108x over previous
//
#include <hip/hip_runtime.h>
#include <cstddef>

#define DEV __device__ __forceinline__

DEV float fexp2(float x) { return __builtin_amdgcn_exp2f(x); }
DEV float frcp(float x)  { return __builtin_amdgcn_rcpf(x); }
DEV float fsigm(float x) { return frcp(1.0f + fexp2(-1.44269504f * x)); }
DEV float ftanh_(float x){ return 1.0f - 2.0f * frcp(1.0f + fexp2(2.88539008f * x)); }

// ---------------------------------------------------------------------------
// Generic fp32 GEMM: C[M,N] = A[M,K] @ W[N,K]^T + bias1 (+bias2), optional relu
// ---------------------------------------------------------------------------
template <int BN, bool RELU>
__global__ __launch_bounds__(256) void gemm_kernel(
    const float* __restrict__ A, const float* __restrict__ W,
    const float* __restrict__ bias1, const float* __restrict__ bias2,
    float* __restrict__ C, int M, int N, int K)
{
    constexpr int BM = 128, BK = 16;
    constexpr int NC = BN / 64;           // col-halves (1 or 2)
    __shared__ float As[BK][BM + 4];
    __shared__ float Bs[BK][BN + 4];

    const int tid = threadIdx.x;
    const int tx = tid & 15, ty = tid >> 4;
    const int m0 = blockIdx.x * BM, n0 = blockIdx.y * BN;

    float acc[2][NC][4][4];
#pragma unroll
    for (int rh = 0; rh < 2; ++rh)
#pragma unroll
        for (int ch = 0; ch < NC; ++ch)
#pragma unroll
            for (int i = 0; i < 4; ++i)
#pragma unroll
                for (int j = 0; j < 4; ++j) acc[rh][ch][i][j] = 0.f;

    for (int k0 = 0; k0 < K; k0 += BK) {
#pragma unroll
        for (int l = 0; l < 2; ++l) {
            int idx = tid + l * 256;
            int row = idx >> 2, kc4 = idx & 3;
            float4 v = *(const float4*)&A[(size_t)(m0 + row) * K + k0 + kc4 * 4];
            As[kc4 * 4 + 0][row] = v.x; As[kc4 * 4 + 1][row] = v.y;
            As[kc4 * 4 + 2][row] = v.z; As[kc4 * 4 + 3][row] = v.w;
        }
#pragma unroll
        for (int l = 0; l < BN / 64; ++l) {
            int idx = tid + l * 256;
            int row = idx >> 2, kc4 = idx & 3;
            float4 v = *(const float4*)&W[(size_t)(n0 + row) * K + k0 + kc4 * 4];
            Bs[kc4 * 4 + 0][row] = v.x; Bs[kc4 * 4 + 1][row] = v.y;
            Bs[kc4 * 4 + 2][row] = v.z; Bs[kc4 * 4 + 3][row] = v.w;
        }
        __syncthreads();
#pragma unroll
        for (int kk = 0; kk < BK; ++kk) {
            const float4 a0 = *(const float4*)&As[kk][ty * 4];
            const float4 a1 = *(const float4*)&As[kk][64 + ty * 4];
            float ar[2][4] = {{a0.x, a0.y, a0.z, a0.w}, {a1.x, a1.y, a1.z, a1.w}};
            float br[NC][4];
            const float4 b0 = *(const float4*)&Bs[kk][tx * 4];
            br[0][0] = b0.x; br[0][1] = b0.y; br[0][2] = b0.z; br[0][3] = b0.w;
            if (NC == 2) {
                const float4 b1 = *(const float4*)&Bs[kk][64 + tx * 4];
                br[1][0] = b1.x; br[1][1] = b1.y; br[1][2] = b1.z; br[1][3] = b1.w;
            }
#pragma unroll
            for (int rh = 0; rh < 2; ++rh)
#pragma unroll
                for (int ch = 0; ch < NC; ++ch)
#pragma unroll
                    for (int i = 0; i < 4; ++i)
#pragma unroll
                        for (int j = 0; j < 4; ++j)
                            acc[rh][ch][i][j] += ar[rh][i] * br[ch][j];
        }
        __syncthreads();
    }

#pragma unroll
    for (int ch = 0; ch < NC; ++ch) {
        int col = n0 + ch * 64 + tx * 4;
        float4 bv = *(const float4*)&bias1[col];
        if (bias2) {
            float4 b2 = *(const float4*)&bias2[col];
            bv.x += b2.x; bv.y += b2.y; bv.z += b2.z; bv.w += b2.w;
        }
#pragma unroll
        for (int rh = 0; rh < 2; ++rh)
#pragma unroll
            for (int i = 0; i < 4; ++i) {
                int row = m0 + rh * 64 + ty * 4 + i;
                float4 r;
                r.x = acc[rh][ch][i][0] + bv.x;
                r.y = acc[rh][ch][i][1] + bv.y;
                r.z = acc[rh][ch][i][2] + bv.z;
                r.w = acc[rh][ch][i][3] + bv.w;
                if (RELU) {
                    r.x = fmaxf(r.x, 0.f); r.y = fmaxf(r.y, 0.f);
                    r.z = fmaxf(r.z, 0.f); r.w = fmaxf(r.w, 0.f);
                }
                *(float4*)&C[(size_t)row * N + col] = r;
            }
    }
}

// ---------------------------------------------------------------------------
__global__ __launch_bounds__(64) void bin_enc_kernel(
    const float* __restrict__ bin_info, const float* __restrict__ W1,
    const float* __restrict__ b1, const float* __restrict__ W2,
    const float* __restrict__ b2, float* __restrict__ BBo)
{
    int b = blockIdx.x, d = threadIdx.x;
    __shared__ float h1[64];
    float x0 = bin_info[b * 2], x1 = bin_info[b * 2 + 1];
    h1[d] = fmaxf(W1[d * 2] * x0 + W1[d * 2 + 1] * x1 + b1[d], 0.f);
    __syncthreads();
    float acc = b2[d];
#pragma unroll 4
    for (int e = 0; e < 64; ++e) acc += W2[d * 64 + e] * h1[e];
    BBo[b * 64 + d] = acc;
}

// ---------------------------------------------------------------------------
__global__ __launch_bounds__(128) void part_enc_kernel(
    const float* __restrict__ parts, const float* __restrict__ W1,
    const float* __restrict__ b1, const float* __restrict__ W2,
    const float* __restrict__ b2, const float* __restrict__ BBi,
    const float* __restrict__ pos_emb, float* __restrict__ X)
{
    __shared__ float W2s[128][129];
    __shared__ float h1[128];
    __shared__ float pin[16];
    int tid = threadIdx.x;
    int b = blockIdx.x >> 3, s0 = (blockIdx.x & 7) * 32;
    for (int l = 0; l < 128; ++l) W2s[l][tid] = W2[l * 128 + tid];
    float w1r[16];
#pragma unroll
    for (int k = 0; k < 16; ++k) w1r[k] = W1[tid * 16 + k];
    float bias1v = b1[tid], bias2v = b2[tid];
    for (int si = 0; si < 32; ++si) {
        int s = s0 + si;
        size_t row = (size_t)b * 256 + s;
        if (tid < 16) pin[tid] = parts[row * 16 + tid];
        __syncthreads();
        float h = bias1v;
#pragma unroll
        for (int k = 0; k < 16; ++k) h += w1r[k] * pin[k];
        h1[tid] = fmaxf(h, 0.f);
        __syncthreads();
        float acc = bias2v;
#pragma unroll 4
        for (int e = 0; e < 128; ++e) acc += W2s[tid][e] * h1[e];
        X[row * 256 + tid] = acc;
        if (tid < 64) {
            X[row * 256 + 128 + tid] = BBi[b * 64 + tid];
            X[row * 256 + 192 + tid] = pos_emb[s * 64 + tid];
        }
        __syncthreads();
    }
}

// ---------------------------------------------------------------------------
__global__ __launch_bounds__(256) void attn_kernel(
    const float* __restrict__ QKV, float* __restrict__ O)
{
    int bh = blockIdx.x;
    int b = bh >> 3, h = bh & 7;
    int s = threadIdx.x;
    __shared__ float k_s[256][36];
    __shared__ float v_s[256][36];
    const float scale = 0.17677669529663687f;
    const float c_log2e = 1.44269504f;

    const float* base = QKV + ((size_t)(b * 256 + s)) * 768 + h * 32;
    float q[32];
#pragma unroll
    for (int d4 = 0; d4 < 8; ++d4) {
        float4 qv = *(const float4*)(base + d4 * 4);
        q[d4 * 4 + 0] = qv.x; q[d4 * 4 + 1] = qv.y;
        q[d4 * 4 + 2] = qv.z; q[d4 * 4 + 3] = qv.w;
        float4 kv = *(const float4*)(base + 256 + d4 * 4);
        *(float4*)&k_s[s][d4 * 4] = kv;
        float4 vv = *(const float4*)(base + 512 + d4 * 4);
        *(float4*)&v_s[s][d4 * 4] = vv;
    }
    __syncthreads();

    float mmax = -1e30f;
    for (int j = 0; j < 256; ++j) {
        float sc = 0.f;
#pragma unroll
        for (int d4 = 0; d4 < 8; ++d4) {
            float4 kv = *(const float4*)&k_s[j][d4 * 4];
            sc += q[d4 * 4 + 0] * kv.x + q[d4 * 4 + 1] * kv.y
                + q[d4 * 4 + 2] * kv.z + q[d4 * 4 + 3] * kv.w;
        }
        mmax = fmaxf(mmax, sc);
    }
    float sum = 0.f;
    float o[32];
#pragma unroll
    for (int d = 0; d < 32; ++d) o[d] = 0.f;
    for (int j = 0; j < 256; ++j) {
        float sc = 0.f;
#pragma unroll
        for (int d4 = 0; d4 < 8; ++d4) {
            float4 kv = *(const float4*)&k_s[j][d4 * 4];
            sc += q[d4 * 4 + 0] * kv.x + q[d4 * 4 + 1] * kv.y
                + q[d4 * 4 + 2] * kv.z + q[d4 * 4 + 3] * kv.w;
        }
        float e = fexp2((sc - mmax) * (scale * c_log2e));
        sum += e;
#pragma unroll
        for (int d4 = 0; d4 < 8; ++d4) {
            float4 vv = *(const float4*)&v_s[j][d4 * 4];
            o[d4 * 4 + 0] += e * vv.x; o[d4 * 4 + 1] += e * vv.y;
            o[d4 * 4 + 2] += e * vv.z; o[d4 * 4 + 3] += e * vv.w;
        }
    }
    float inv = 1.0f / sum;
    float* op = O + ((size_t)(b * 256 + s)) * 256 + h * 32;
#pragma unroll
    for (int d4 = 0; d4 < 8; ++d4) {
        float4 r;
        r.x = o[d4 * 4 + 0] * inv; r.y = o[d4 * 4 + 1] * inv;
        r.z = o[d4 * 4 + 2] * inv; r.w = o[d4 * 4 + 3] * inv;
        *(float4*)(op + d4 * 4) = r;
    }
}

// ---------------------------------------------------------------------------
__global__ __launch_bounds__(256) void add_ln_kernel(
    float* __restrict__ X, const float* __restrict__ R,
    const float* __restrict__ g, const float* __restrict__ beta)
{
    size_t row = blockIdx.x;
    int d = threadIdx.x;
    float y = X[row * 256 + d] + R[row * 256 + d];
    float s = y, s2 = y * y;
#pragma unroll
    for (int o = 32; o; o >>= 1) {
        s += __shfl_down(s, o);
        s2 += __shfl_down(s2, o);
    }
    __shared__ float red[8];
    int wid = d >> 6, lane = d & 63;
    if (lane == 0) { red[wid] = s; red[4 + wid] = s2; }
    __syncthreads();
    if (d == 0) {
        float a = 0.f, b2 = 0.f;
        for (int w = 0; w < 4; ++w) { a += red[w]; b2 += red[4 + w]; }
        red[0] = a * (1.f / 256.f);
        red[1] = b2 * (1.f / 256.f);
    }
    __syncthreads();
    float m = red[0];
    float var = red[1] - m * m;
    float inv = rsqrtf(var + 1e-5f);
    X[row * 256 + d] = (y - m) * inv * g[d] + beta[d];
}

// ---------------------------------------------------------------------------
__global__ __launch_bounds__(256) void gather_kernel(
    const float* __restrict__ X, const int* __restrict__ target,
    float* __restrict__ Xg)
{
    int row = blockIdx.x;
    int b = row >> 8, t = row & 255;
    int d = threadIdx.x;
    float val = 0.f;
    if (t > 0) {
        int src = target[b * 256 + t - 1];
        val = X[((size_t)b * 256 + src) * 256 + d];
    }
    Xg[(size_t)row * 256 + d] = val;
}

// ---------------------------------------------------------------------------
// Whh [1024,256] fp32 -> WT bf16 [256,1024]: WT[k*1024+j] = bf16(Whh[j*256+k])
// ---------------------------------------------------------------------------
__global__ __launch_bounds__(256) void wcvt_kernel(
    const float* __restrict__ Whh, unsigned short* __restrict__ WT)
{
    int o = blockIdx.x * 256 + threadIdx.x;   // 0..262143
    int k = o >> 10, j = o & 1023;
    unsigned int u = __float_as_uint(Whh[j * 256 + k]);
    u += 0x7fffu + ((u >> 16) & 1u);          // RNE to bf16
    WT[o] = (unsigned short)(u >> 16);
}

// ---------------------------------------------------------------------------
// LSTM recurrence: 1 block/batch, 1024 threads (16 waves).
// thread = (kq = tid>>8, j4 = tid&255): partial over k in [kq*64,kq*64+64)
// for gate rows [4*j4, 4*j4+4), weights bf16 from WT[k][j].
// Reduce 4 partials in LDS, then threads 0..255 do the cell update.
// ---------------------------------------------------------------------------
__global__ __launch_bounds__(1024) void lstm_kernel(
    const float* __restrict__ g_in, const unsigned short* __restrict__ WT,
    float* __restrict__ HALL)
{
    int b = blockIdx.x;
    int tid = threadIdx.x;
    int j4 = tid & 255, kq = tid >> 8;
    __shared__ float h_s[256];
    __shared__ float gpart[4][1024];
    float c = 0.f;
    if (tid < 256) h_s[tid] = 0.f;
    __syncthreads();

    const unsigned short* wbase = WT + (size_t)(kq * 64) * 1024 + j4 * 4;

    for (int t = 0; t < 256; ++t) {
        const float* gin = g_in + (((size_t)b << 8) + t) * 1024;
        // prefetch the 4 gate biases this thread's cell will need (tid<256)
        float gi0 = 0.f, gi1 = 0.f, gi2 = 0.f, gi3 = 0.f;
        if (tid < 256) {
            gi0 = gin[tid];       gi1 = gin[tid + 256];
            gi2 = gin[tid + 512]; gi3 = gin[tid + 768];
        }
        float4 acc = make_float4(0.f, 0.f, 0.f, 0.f);
        const int kbase = kq * 64;
#pragma unroll 8
        for (int k = 0; k < 64; ++k) {
            uint2 w = *(const uint2*)(wbase + (size_t)k * 1024);
            float hk = h_s[kbase + k];
            float w0 = __uint_as_float(w.x << 16);
            float w1 = __uint_as_float(w.x & 0xffff0000u);
            float w2 = __uint_as_float(w.y << 16);
            float w3 = __uint_as_float(w.y & 0xffff0000u);
            acc.x += w0 * hk; acc.y += w1 * hk;
            acc.z += w2 * hk; acc.w += w3 * hk;
        }
        *(float4*)&gpart[kq][j4 * 4] = acc;
        __syncthreads();
        if (tid < 256) {
            int j = tid;
            float ig = gi0 + gpart[0][j] + gpart[1][j] + gpart[2][j] + gpart[3][j];
            float fg = gi1 + gpart[0][j + 256] + gpart[1][j + 256]
                           + gpart[2][j + 256] + gpart[3][j + 256];
            float gg = gi2 + gpart[0][j + 512] + gpart[1][j + 512]
                           + gpart[2][j + 512] + gpart[3][j + 512];
            float og = gi3 + gpart[0][j + 768] + gpart[1][j + 768]
                           + gpart[2][j + 768] + gpart[3][j + 768];
            c = fsigm(fg) * c + fsigm(ig) * ftanh_(gg);
            float h = fsigm(og) * ftanh_(c);
            h_s[j] = h;
            HALL[(((size_t)b << 8) + t) * 256 + j] = h;
        }
        __syncthreads();
    }
}

// ---------------------------------------------------------------------------
__global__ __launch_bounds__(256) void pointer_kernel(
    const float* __restrict__ HP, const float* __restrict__ EP,
    const float* __restrict__ v, float* __restrict__ out)
{
    int b = blockIdx.z, tt = blockIdx.y, it = blockIdx.x;
    __shared__ float hp_s[16][260];
    __shared__ float ep_s[16][260];
    __shared__ float v_s[256];
    int tid = threadIdx.x;
    const float* hpb = HP + ((size_t)b * 256 + tt * 16) * 256;
    const float* epb = EP + ((size_t)b * 256 + it * 16) * 256;
#pragma unroll
    for (int l = 0; l < 4; ++l) {
        int idx = tid + l * 256;
        int r = idx >> 6, c4 = idx & 63;
        float4 hv = *(const float4*)(hpb + r * 256 + c4 * 4);
        *(float4*)&hp_s[r][c4 * 4] = hv;
        float4 ev = *(const float4*)(epb + r * 256 + c4 * 4);
        *(float4*)&ep_s[r][c4 * 4] = ev;
    }
    v_s[tid] = v[tid];
    __syncthreads();
    int tl = tid >> 4, il = tid & 15;
    float acc = 0.f;
#pragma unroll 4
    for (int d = 0; d < 256; ++d)
        acc += v_s[d] * ftanh_(hp_s[tl][d] + ep_s[il][d]);
    out[((size_t)b * 256 + tt * 16 + tl) * 256 + it * 16 + il] = acc;
}

// ---------------------------------------------------------------------------
extern "C" void kernel_launch(void* const* d_in, const int* in_sizes, int n_in,
                              void* d_out, int out_size, void* d_ws, size_t ws_size,
                              hipStream_t stream)
{
    const float* parts    = (const float*)d_in[0];
    const float* bin_info = (const float*)d_in[1];
    const int*   target   = (const int*)d_in[2];
    const float* pe_W1 = (const float*)d_in[3];
    const float* pe_b1 = (const float*)d_in[4];
    const float* pe_W2 = (const float*)d_in[5];
    const float* pe_b2 = (const float*)d_in[6];
    const float* be_W1 = (const float*)d_in[7];
    const float* be_b1 = (const float*)d_in[8];
    const float* be_W2 = (const float*)d_in[9];
    const float* be_b2 = (const float*)d_in[10];
    const float* pos_emb = (const float*)d_in[11];
    const float* tr_Wqkv = (const float*)d_in[12];
    const float* tr_bqkv = (const float*)d_in[13];
    const float* tr_Wo   = (const float*)d_in[14];
    const float* tr_bo   = (const float*)d_in[15];
    const float* tr_ln1_g = (const float*)d_in[16];
    const float* tr_ln1_b = (const float*)d_in[17];
    const float* tr_ff_W1 = (const float*)d_in[18];
    const float* tr_ff_b1 = (const float*)d_in[19];
    const float* tr_ff_W2 = (const float*)d_in[20];
    const float* tr_ff_b2 = (const float*)d_in[21];
    const float* tr_ln2_g = (const float*)d_in[22];
    const float* tr_ln2_b = (const float*)d_in[23];
    const float* lstm_Wih = (const float*)d_in[24];
    const float* lstm_Whh = (const float*)d_in[25];
    const float* lstm_bih = (const float*)d_in[26];
    const float* lstm_bhh = (const float*)d_in[27];
    const float* ptr_W = (const float*)d_in[28];
    const float* ptr_b = (const float*)d_in[29];
    const float* ptr_v = (const float*)d_in[30];

    float* ws = (float*)d_ws;
    float* X     = ws;                   // 2,097,152
    float* S1    = X + 2097152;          // 8,388,608
    float* S2    = S1 + 8388608;         // 2,097,152
    float* EPROJ = S2 + 2097152;         // 2,097,152
    float* BBuf  = EPROJ + 2097152;      // 2048
    float* WHHT  = BBuf + 2048;          // 262,144 floats reserved (bf16 uses half)
    float* HALL  = WHHT + 262144;        // 2,097,152

    // ---- encoders ----
    bin_enc_kernel<<<32, 64, 0, stream>>>(bin_info, be_W1, be_b1, be_W2, be_b2, BBuf);
    part_enc_kernel<<<256, 128, 0, stream>>>(parts, pe_W1, pe_b1, pe_W2, pe_b2,
                                             BBuf, pos_emb, X);

    // ---- transformer layers ----
    for (int l = 0; l < 3; ++l) {
        gemm_kernel<128, false><<<dim3(64, 6), 256, 0, stream>>>(
            X, tr_Wqkv + (size_t)l * 768 * 256, tr_bqkv + l * 768, nullptr,
            S1, 8192, 768, 256);
        attn_kernel<<<256, 256, 0, stream>>>(S1, S2);
        gemm_kernel<64, false><<<dim3(64, 4), 256, 0, stream>>>(
            S2, tr_Wo + (size_t)l * 256 * 256, tr_bo + l * 256, nullptr,
            S1, 8192, 256, 256);
        add_ln_kernel<<<8192, 256, 0, stream>>>(X, S1, tr_ln1_g + l * 256,
                                                tr_ln1_b + l * 256);
        gemm_kernel<128, true><<<dim3(64, 4), 256, 0, stream>>>(
            X, tr_ff_W1 + (size_t)l * 512 * 256, tr_ff_b1 + l * 512, nullptr,
            S1, 8192, 512, 256);
        gemm_kernel<64, false><<<dim3(64, 4), 256, 0, stream>>>(
            S1, tr_ff_W2 + (size_t)l * 256 * 512, tr_ff_b2 + l * 256, nullptr,
            S2, 8192, 256, 512);
        add_ln_kernel<<<8192, 256, 0, stream>>>(X, S2, tr_ln2_g + l * 256,
                                                tr_ln2_b + l * 256);
    }

    // ---- pointer decode ----
    gemm_kernel<64, false><<<dim3(64, 4), 256, 0, stream>>>(
        X, ptr_W, ptr_b, nullptr, EPROJ, 8192, 256, 256);
    gather_kernel<<<8192, 256, 0, stream>>>(X, target, S2);
    gemm_kernel<128, false><<<dim3(64, 8), 256, 0, stream>>>(
        S2, lstm_Wih, lstm_bih, lstm_bhh, S1, 8192, 1024, 256);
    wcvt_kernel<<<1024, 256, 0, stream>>>(lstm_Whh, (unsigned short*)WHHT);
    lstm_kernel<<<32, 1024, 0, stream>>>(S1, (const unsigned short*)WHHT, HALL);
    gemm_kernel<64, false><<<dim3(64, 4), 256, 0, stream>>>(
        HALL, ptr_W, ptr_b, nullptr, S2, 8192, 256, 256);
    pointer_kernel<<<dim3(16, 16, 32), 256, 0, stream>>>(S2, EPROJ, ptr_v,
                                                         (float*)d_out);
}